// Round 15
// baseline (200.515 us; speedup 1.0000x reference)
//
#include <hip/hip_runtime.h>
#include <stdint.h>

#define NH 12
#define HD 64
#define NB 4
#define SEQ 1024
#define CDIM 768
#define MTOT (NB*SEQ)
#define MC   (MTOT*CDIM)      /* 3145728 */
#define LC   (SEQ*CDIM)       /* 786432  */
#define WSZ  (CDIM*CDIM)      /* 589824  */
#define LST  104              /* attn P LDS row stride (shorts) */
#define EST  136              /* epilogue LDS row stride (shorts) */
#define L2E  1.44269504f
#define BHSZ (SEQ*HD)         /* 65536 shorts per (b,h) */
#define PTSZ ((size_t)NH*SEQ*SEQ)  /* posT elements (u16) = 12.58M */
#define LTS 68                     /* LDS transpose row stride (floats) */

typedef __attribute__((ext_vector_type(4))) float f32x4;
typedef __attribute__((ext_vector_type(8))) __bf16 bf16x8;
typedef __attribute__((ext_vector_type(8))) short short8;
typedef __attribute__((ext_vector_type(4))) unsigned short ushort4v;
typedef unsigned short u16;

static __device__ __forceinline__ f32x4 mfma16(short8 a, short8 b, f32x4 c) {
  return __builtin_amdgcn_mfma_f32_16x16x32_bf16(
      __builtin_bit_cast(bf16x8, a), __builtin_bit_cast(bf16x8, b), c, 0, 0, 0);
}
static __device__ __forceinline__ u16 f2bf(float f) {
  unsigned u = __float_as_uint(f);
  u += 0x7FFFu + ((u >> 16) & 1u);
  return (u16)(u >> 16);
}
static __device__ __forceinline__ float bf2f(u16 h) {
  return __uint_as_float(((unsigned)h) << 16);
}
static __device__ __forceinline__ void lds_load16(const void* g, void* l) {
  __builtin_amdgcn_global_load_lds(
      (const __attribute__((address_space(1))) void*)g,
      (__attribute__((address_space(3))) void*)l, 16, 0, 0);
}

// ---- fused prep: Xq/Xk/Xv bf16 tokens + all weights/bias -> bf16 ----
#define PREP_BLKS (MC / 4 / 256)
#define CONV_N4   ((4 * WSZ + CDIM) / 4)
#define CONV_BLKS ((CONV_N4 + 255) / 256)
__global__ __launch_bounds__(256) void prep_all(
    const float* __restrict__ xp, const float* __restrict__ qp,
    const float* __restrict__ kp, const float* __restrict__ Wq,
    const float* __restrict__ Wk, const float* __restrict__ Wv,
    const float* __restrict__ Wp, const float* __restrict__ bp,
    u16* __restrict__ Xq, u16* __restrict__ Xk, u16* __restrict__ Xv,
    u16* __restrict__ Wb) {
  int bid = blockIdx.x;
  if (bid < PREP_BLKS) {
    int i4 = bid * 256 + threadIdx.x;
    int a4 = i4 % (LC / 4);
    f32x4 xx = ((const f32x4*)xp)[i4];
    f32x4 qq = ((const f32x4*)qp)[a4];
    f32x4 kk = ((const f32x4*)kp)[a4];
    ushort4v oq, ok, ov;
#pragma unroll
    for (int j = 0; j < 4; j++) {
      oq[j] = f2bf(xx[j] + qq[j]);
      ok[j] = f2bf(xx[j] + kk[j]);
      ov[j] = f2bf(xx[j]);
    }
    ((ushort4v*)Xq)[i4] = oq;
    ((ushort4v*)Xk)[i4] = ok;
    ((ushort4v*)Xv)[i4] = ov;
  } else {
    int i4 = (bid - PREP_BLKS) * 256 + threadIdx.x;
    if (i4 >= CONV_N4) return;
    int sel = i4 / (WSZ / 4);
    int off = i4 - sel * (WSZ / 4);
    const float* src = sel == 0 ? Wq : sel == 1 ? Wk : sel == 2 ? Wv
                     : sel == 3 ? Wp : bp;
    f32x4 v = ((const f32x4*)src)[off];
    ushort4v o;
#pragma unroll
    for (int j = 0; j < 4; j++) o[j] = f2bf(v[j]);
    ((ushort4v*)Wb)[i4] = o;
  }
}

// ---- 128x128 (K=768) bf16 GEMM core, DOUBLE-BUFFERED 2-phase:
// per K-step: issue next tile's 8 global_load_lds into buf^1, then
// s_waitcnt vmcnt(8) (waits only PREVIOUS step's loads, which had a full
// compute phase to land), raw s_barrier (no compiler vmcnt(0) drain),
// 32 MFMAs from buf, lgkmcnt(0)+barrier. LDS 64KB (2 x {A 16KB + B 16KB}).
// vs round-13's 64x128: 2x MFMA per barrier-pair, half the blocks.
static __device__ __forceinline__ void gemm_core128_db(
    const u16* __restrict__ Ab, const u16* __restrict__ Wb,
    short* S, f32x4 acc[4][4]) {
  const int t = threadIdx.x;
  const int lane = t & 63, w = t >> 6, quad = lane >> 4, l16 = lane & 15;
  const int wm = (w >> 1) * 64, wn = (w & 1) * 64;
  const int rowq = t >> 2, chunk = (t & 3) * 8;   // 64 rows/quarter, 32-col half

#define QK_STAGE(K0, BUF) do {                                               \
    short* As_ = S + (BUF) * 16384;                                          \
    short* Bs_ = As_ + 8192;                                                 \
    _Pragma("unroll")                                                        \
    for (int hh = 0; hh < 2; hh++)                                           \
      _Pragma("unroll")                                                      \
      for (int p = 0; p < 2; p++) {                                          \
        const u16* ga = Ab + (p * 64 + rowq) * CDIM + (K0) + hh * 32 + chunk;\
        const u16* gb = Wb + (p * 64 + rowq) * CDIM + (K0) + hh * 32 + chunk;\
        lds_load16(ga, (char*)As_ + hh * 8192 + p * 4096 + t * 16);          \
        lds_load16(gb, (char*)Bs_ + hh * 8192 + p * 4096 + t * 16);          \
      }                                                                      \
  } while (0)

  QK_STAGE(0, 0);
#pragma unroll 1
  for (int ks = 0; ks < 12; ++ks) {
    const int cur = ks & 1;
    if (ks < 11) {
      QK_STAGE((ks + 1) * 64, cur ^ 1);
      asm volatile("s_waitcnt vmcnt(8)" ::: "memory");
    } else {
      asm volatile("s_waitcnt vmcnt(0)" ::: "memory");
    }
    __builtin_amdgcn_s_barrier();
    __builtin_amdgcn_sched_barrier(0);
    const short* Asb = S + cur * 16384;
    const short* Bsb = Asb + 8192;
#pragma unroll
    for (int hh = 0; hh < 2; hh++) {
      const short* Ah = Asb + hh * 4096;
      const short* Bh = Bsb + hh * 4096;
      short8 af[4], bw[4];
#pragma unroll
      for (int i = 0; i < 4; i++)
        af[i] = *(const short8*)(Ah + (wm + i * 16 + l16) * 32 + quad * 8);
#pragma unroll
      for (int j = 0; j < 4; j++)
        bw[j] = *(const short8*)(Bh + (wn + j * 16 + l16) * 32 + quad * 8);
#pragma unroll
      for (int i = 0; i < 4; i++)
#pragma unroll
        for (int j = 0; j < 4; j++)
          acc[i][j] = mfma16(af[i], bw[j], acc[i][j]);
    }
    // all ds_reads done before next step overwrites buf cur^1
    asm volatile("s_waitcnt lgkmcnt(0)" ::: "memory");
    __builtin_amdgcn_s_barrier();
    __builtin_amdgcn_sched_barrier(0);
  }
#undef QK_STAGE
}

// ---- QKV projections (128x128 tiles, 2-phase) + pos repack (z==3).
// z=0:Q (pre-scaled 0.125, row-major)  z=1:K fragment  z=2:V fragment
// (128-row epilogue validated in rounds 0-2; EST=136, max idx 17399 < 32768)
// z=3: pos (f32 [h][row][col]) -> posT (bf16*L2E) fragment order, 192 blocks
// x 64 chunks.
__global__ __launch_bounds__(256) void gemm_qkv(
    const u16* __restrict__ Xq, const u16* __restrict__ Xk, const u16* __restrict__ Xv,
    const u16* __restrict__ Wq, const u16* __restrict__ Wk, const u16* __restrict__ Wv,
    u16* __restrict__ Q, u16* __restrict__ K, u16* __restrict__ Vt,
    const float* __restrict__ pos, u16* __restrict__ posT) {
  __shared__ __align__(16) short S[32768];   // 64KB: 2 x (A 8192 + B 8192)
  if (blockIdx.z == 3) {
    const int t = threadIdx.x, wv = t >> 6, lane = t & 63;
    const int flat = blockIdx.y * 6 + blockIdx.x;   // 0..191
    const int rr = lane >> 2, cq = lane & 3;
    const int quad = lane >> 4, l16 = lane & 15;
    float* Lw = (float*)S + wv * (16 * LTS);
#pragma unroll 1
    for (int c = 0; c < 16; ++c) {
      const int chunk = flat * 64 + wv * 16 + c;    // 0..12287
      const int h = chunk >> 10, rem = chunk & 1023;
      const int rb = rem >> 4, kt = rem & 15;
      const float* src = pos + (size_t)h * SEQ * SEQ
                         + (size_t)(rb * 16) * SEQ + kt * 64;
#pragma unroll
      for (int u = 0; u < 4; u++) {
        f32x4 v = *(const f32x4*)(src + rr * SEQ + cq * 16 + u * 4);
        *(f32x4*)(Lw + rr * LTS + cq * 16 + u * 4) = v;
      }
      __builtin_amdgcn_s_waitcnt(0xC07F);   // lgkmcnt(0), per-wave
      short8 s0, s1;
#pragma unroll
      for (int j = 0; j < 2; j++)
#pragma unroll
        for (int r = 0; r < 4; r++) {
          s0[j * 4 + r] = (short)f2bf(Lw[(quad * 4 + r) * LTS + j * 16 + l16] * L2E);
          s1[j * 4 + r] = (short)f2bf(Lw[(quad * 4 + r) * LTS + (j + 2) * 16 + l16] * L2E);
        }
      u16* dst = posT + (size_t)chunk * 1024 + lane * 16;
      *(short8*)dst = s0;
      *(short8*)(dst + 8) = s1;
      __builtin_amdgcn_s_waitcnt(0xC07F);   // drain LDS reads before overwrite
    }
    return;
  }

  const int z = blockIdx.z;
  const int m0 = blockIdx.y * 128, n0 = blockIdx.x * 128;
  const u16* A = (z == 0 ? Xq : z == 1 ? Xk : Xv) + m0 * CDIM;
  const u16* W = (z == 0 ? Wq : z == 1 ? Wk : Wv) + n0 * CDIM;
  f32x4 acc[4][4];
#pragma unroll
  for (int i = 0; i < 4; i++)
#pragma unroll
    for (int j = 0; j < 4; j++) acc[i][j] = 0.f;
  gemm_core128_db(A, W, S, acc);

  const int t = threadIdx.x, lane = t & 63, w = t >> 6;
  const int quad = lane >> 4, l16 = lane & 15;
  const int wm = (w >> 1) * 64, wn = (w & 1) * 64;
  const float qs = (z == 0) ? 0.125f : 1.0f;

  __syncthreads();   // all compute done before S is reused by the epilogue
#pragma unroll
  for (int i = 0; i < 4; i++)
#pragma unroll
    for (int j = 0; j < 4; j++)
#pragma unroll
      for (int r = 0; r < 4; r++) {
        int mr = wm + i * 16 + quad * 4 + r;
        int nc = wn + j * 16 + l16;
        if (z < 2) S[mr * EST + nc] = (short)f2bf(acc[i][j][r] * qs);
        else       S[nc * EST + mr] = (short)f2bf(acc[i][j][r]);
      }
  __syncthreads();

  const int row = t >> 3, ch = t & 7;
  const int b = m0 >> 10, lbase = m0 & 1023;
  if (z == 0) {
#pragma unroll
    for (int cp = 0; cp < 2; cp++) {
      int h = (n0 >> 6) + cp;
#pragma unroll
      for (int rp = 0; rp < 4; rp++) {
        int mr = row + rp * 32;
        short8 v = *(const short8*)(S + mr * EST + cp * 64 + ch * 8);
        *(short8*)(Q + ((((size_t)(b * NH + h)) << 10) + lbase + mr) * HD + ch * 8) = v;
      }
    }
  } else if (z == 1) {
#pragma unroll
    for (int cp = 0; cp < 2; cp++) {
      int h = (n0 >> 6) + cp;
      u16* Kp = K + (size_t)(b * NH + h) * BHSZ;
#pragma unroll
      for (int rp = 0; rp < 4; rp++) {
        int mr = row + rp * 32;
        int tok = lbase + mr;
        short8 v = *(const short8*)(S + mr * EST + cp * 64 + ch * 8);
        *(short8*)(Kp + (((tok >> 4) * 8 + ch) * 16 + (tok & 15)) * 8) = v;
      }
    }
  } else {
#pragma unroll
    for (int rp = 0; rp < 4; rp++) {
      int rn = row + rp * 32;            // local d-row of transposed tile (n-dim)
      int h = (n0 + rn) >> 6, d = rn & 63;
      u16* Vp = Vt + (size_t)(b * NH + h) * BHSZ;
      int jv = d >> 4, ld16 = d & 15;
#pragma unroll
      for (int cp = 0; cp < 2; cp++) {
        int tok = lbase + cp * 64 + ch * 8;
        short8 v = *(const short8*)(S + rn * EST + cp * 64 + ch * 8);
        *(short8*)(Vp + ((((tok >> 6) * 4 + jv) * 8 + ((tok >> 3) & 7)) * 16 + ld16) * 8) = v;
      }
    }
  }
}

// ---- flash attention: round-0 schedule, pos from posT (2 short8/tile) ----
__global__ __launch_bounds__(256, 3) void attn(
    const u16* __restrict__ Q, const u16* __restrict__ Kf, const u16* __restrict__ Vf,
    const u16* __restrict__ posT, u16* __restrict__ O) {
  __shared__ __align__(16) short Ps[4 * 16 * LST];
  const int t = threadIdx.x, lane = t & 63, w = t >> 6;
  const int quad = lane >> 4, l16 = lane & 15;

  // XCD-clustered decode (round-robin lid%8 -> XCD; permutation only)
  const int lid = blockIdx.x;
  const int k8 = lid & 7, m = lid >> 3;
  const int g = k8 * 24 + (m >> 2), b = m & 3;
  const int h = g >> 4, qt = g & 15;
  const int bh = b * NH + h;
  const int q0 = qt * 64 + w * 16;

  const u16* Kg = Kf + (size_t)bh * BHSZ;
  const u16* Vg = Vf + (size_t)bh * BHSZ;
  const u16* Tg = posT + ((size_t)(h * 1024 + (qt * 4 + w) * 16)) * 1024
                  + lane * 16;
  short* Pw = Ps + w * 16 * LST;
  const int fo = quad * 128 + l16 * 8;   // fragment offset (shorts)

  const u16* Qg = Q + ((size_t)bh * SEQ + q0) * HD;
  const short8 qa0 = *(const short8*)(Qg + l16 * HD + quad * 8);
  const short8 qa1 = *(const short8*)(Qg + l16 * HD + 32 + quad * 8);

  f32x4 o[4];
  float lrow[4];
#pragma unroll
  for (int j = 0; j < 4; j++) o[j] = 0.f;
#pragma unroll
  for (int r = 0; r < 4; r++) lrow[r] = 0.f;

  short8 kb0[4], kb1[4];
  short8 pt0, pt1;
#pragma unroll
  for (int j = 0; j < 4; j++) {
    kb0[j] = *(const short8*)(Kg + j * 1024 + fo);
    kb1[j] = *(const short8*)(Kg + j * 1024 + 512 + fo);
  }
  pt0 = *(const short8*)(Tg);
  pt1 = *(const short8*)(Tg + 8);

#pragma unroll 1
  for (int kt = 0; kt < 16; ++kt) {
    const int kbase = kt * 4096;
    short8 vb0[4], vb1[4];
#pragma unroll
    for (int j = 0; j < 4; j++) {
      vb0[j] = *(const short8*)(Vg + kbase + j * 1024 + fo);
      vb1[j] = *(const short8*)(Vg + kbase + j * 1024 + 512 + fo);
    }
    f32x4 s[4];
#pragma unroll
    for (int j = 0; j < 4; j++) {
      f32x4 zz = 0.f;
      s[j] = mfma16(qa1, kb1[j], mfma16(qa0, kb0[j], zz));
    }
#pragma unroll
    for (int j = 0; j < 2; j++)
#pragma unroll
      for (int r = 0; r < 4; r++) {
        float pv = bf2f((u16)pt0[j * 4 + r]);
        float e = __builtin_amdgcn_exp2f(fmaf(s[j][r], L2E, pv));
        unsigned bits = __float_as_uint(e);
        Pw[(quad * 4 + r) * LST + j * 16 + l16] = (short)(bits >> 16);
        lrow[r] += __uint_as_float(bits & 0xFFFF0000u);
      }
#pragma unroll
    for (int j = 2; j < 4; j++)
#pragma unroll
      for (int r = 0; r < 4; r++) {
        float pv = bf2f((u16)pt1[(j - 2) * 4 + r]);
        float e = __builtin_amdgcn_exp2f(fmaf(s[j][r], L2E, pv));
        unsigned bits = __float_as_uint(e);
        Pw[(quad * 4 + r) * LST + j * 16 + l16] = (short)(bits >> 16);
        lrow[r] += __uint_as_float(bits & 0xFFFF0000u);
      }
    if (kt < 15) {
      const int nb = kbase + 4096;
#pragma unroll
      for (int j = 0; j < 4; j++) {
        kb0[j] = *(const short8*)(Kg + nb + j * 1024 + fo);
        kb1[j] = *(const short8*)(Kg + nb + j * 1024 + 512 + fo);
      }
      pt0 = *(const short8*)(Tg + (kt + 1) * 1024);
      pt1 = *(const short8*)(Tg + (kt + 1) * 1024 + 8);
    }
    const short8 pa0 = *(const short8*)(Pw + l16 * LST + quad * 8);
    const short8 pa1 = *(const short8*)(Pw + l16 * LST + 32 + quad * 8);
#pragma unroll
    for (int j = 0; j < 4; j++)
      o[j] = mfma16(pa1, vb1[j], mfma16(pa0, vb0[j], o[j]));
  }

#pragma unroll
  for (int off = 1; off < 16; off <<= 1)
#pragma unroll
    for (int r = 0; r < 4; r++) lrow[r] += __shfl_xor(lrow[r], off);

  u16* Og = O + ((size_t)b * SEQ + q0) * CDIM + h * HD;
  float inv[4];
#pragma unroll
  for (int r = 0; r < 4; r++) inv[r] = 1.0f / lrow[r];
#pragma unroll
  for (int j = 0; j < 4; j++)
#pragma unroll
    for (int r = 0; r < 4; r++)
      Og[(quad * 4 + r) * CDIM + j * 16 + l16] = f2bf(o[j][r] * inv[r]);
}

// ---- output projection + bias, FP32 output. 64x64 tiles, 768 blocks = 3/CU.
__global__ __launch_bounds__(256) void gemm_proj(
    const u16* __restrict__ Oin, const u16* __restrict__ Wp,
    const u16* __restrict__ bp, float* __restrict__ out) {
  __shared__ __align__(16) short As[4096], Bs[4096];   // 16KB
  const int t = threadIdx.x;
  const int lane = t & 63, w = t >> 6, quad = lane >> 4, l16 = lane & 15;
  const int wm = (w >> 1) * 32, wn = (w & 1) * 32;
  const int row4 = t >> 2, chunk = (t & 3) * 8;
  const int m0 = blockIdx.y * 64, n0 = blockIdx.x * 64;
  const u16* Ab = Oin + m0 * CDIM;
  const u16* Wb = Wp + n0 * CDIM;
  f32x4 acc[2][2];
#pragma unroll
  for (int i = 0; i < 2; i++)
#pragma unroll
    for (int j = 0; j < 2; j++) acc[i][j] = 0.f;

  for (int k0 = 0; k0 < CDIM; k0 += 64) {
#pragma unroll
    for (int hh = 0; hh < 2; hh++) {
      const u16* ga = Ab + row4 * CDIM + k0 + hh * 32 + chunk;
      const u16* gb = Wb + row4 * CDIM + k0 + hh * 32 + chunk;
      lds_load16(ga, (char*)As + hh * 4096 + t * 16);
      lds_load16(gb, (char*)Bs + hh * 4096 + t * 16);
    }
    __syncthreads();
#pragma unroll
    for (int hh = 0; hh < 2; hh++) {
      const short* Ah = As + hh * 2048;
      const short* Bh = Bs + hh * 2048;
      short8 af[2], bw[2];
#pragma unroll
      for (int i = 0; i < 2; i++)
        af[i] = *(const short8*)(Ah + (wm + i * 16 + l16) * 32 + quad * 8);
#pragma unroll
      for (int j = 0; j < 2; j++)
        bw[j] = *(const short8*)(Bh + (wn + j * 16 + l16) * 32 + quad * 8);
#pragma unroll
      for (int i = 0; i < 2; i++)
#pragma unroll
        for (int j = 0; j < 2; j++)
          acc[i][j] = mfma16(af[i], bw[j], acc[i][j]);
    }
    __syncthreads();
  }

#pragma unroll
  for (int i = 0; i < 2; i++) {
    int mrow = m0 + wm + i * 16 + quad * 4;
#pragma unroll
    for (int j = 0; j < 2; j++) {
      int n = n0 + wn + j * 16 + l16;
      float bias = bf2f(bp[n]);
#pragma unroll
      for (int r = 0; r < 4; r++)
        out[(mrow + r) * CDIM + n] = acc[i][j][r] + bias;
    }
  }
}

extern "C" void kernel_launch(void* const* d_in, const int* in_sizes, int n_in,
                              void* d_out, int out_size, void* d_ws, size_t ws_size,
                              hipStream_t stream) {
  (void)in_sizes; (void)n_in; (void)out_size;
  const size_t OFF_XQ = 0, OFF_XK = (size_t)MC, OFF_XV = 2ull * MC,
               OFF_Q = 3ull * MC, OFF_K = 4ull * MC, OFF_VT = 5ull * MC,
               OFF_W = 6ull * MC, OFF_PT = OFF_W + 4ull * WSZ + 1024,
               TOT = OFF_PT + PTSZ;
  if (ws_size < TOT * sizeof(u16)) return;

  u16* ws = (u16*)d_ws;
  u16 *Xq = ws + OFF_XQ, *Xk = ws + OFF_XK, *Xv = ws + OFF_XV;
  u16 *Qb = ws + OFF_Q, *Kb = ws + OFF_K, *Vt = ws + OFF_VT;
  u16 *Wb = ws + OFF_W, *Pt = ws + OFF_PT;
  u16 *Wqb = Wb, *Wkb = Wb + WSZ, *Wvb = Wb + 2ull * WSZ,
      *Wpb = Wb + 3ull * WSZ, *bpb = Wb + 4ull * WSZ;
  u16* Ob = Xq;

  prep_all<<<PREP_BLKS + CONV_BLKS, 256, 0, stream>>>(
      (const float*)d_in[0], (const float*)d_in[1], (const float*)d_in[2],
      (const float*)d_in[4], (const float*)d_in[5], (const float*)d_in[6],
      (const float*)d_in[7], (const float*)d_in[8], Xq, Xk, Xv, Wb);
  gemm_qkv<<<dim3(6, 32, 4), 256, 0, stream>>>(Xq, Xk, Xv, Wqb, Wkb, Wvb,
                                               Qb, Kb, Vt,
                                               (const float*)d_in[3], Pt);
  attn<<<dim3(768), 256, 0, stream>>>(Qb, Kb, Vt, Pt, Ob);
  gemm_proj<<<dim3(12, 64), 256, 0, stream>>>(Ob, Wpb, bpb, (float*)d_out);
}

// Round 16
// 196.048 us; speedup vs baseline: 1.0228x; 1.0228x over previous
//
#include <hip/hip_runtime.h>
#include <stdint.h>

#define NH 12
#define HD 64
#define NB 4
#define SEQ 1024
#define CDIM 768
#define MTOT (NB*SEQ)
#define MC   (MTOT*CDIM)      /* 3145728 */
#define LC   (SEQ*CDIM)       /* 786432  */
#define WSZ  (CDIM*CDIM)      /* 589824  */
#define LST  104              /* attn P LDS row stride (shorts) */
#define EST  136              /* epilogue LDS row stride (shorts), z<2 */
#define VST  72               /* transposed-V epilogue row stride (64 tok + 8 pad) */
#define L2E  1.44269504f
#define BHSZ (SEQ*HD)         /* 65536 shorts per (b,h) */
#define PTSZ ((size_t)NH*SEQ*SEQ)  /* posT elements (u16) = 12.58M */
#define LTS 68                     /* LDS transpose row stride (floats) */

typedef __attribute__((ext_vector_type(4))) float f32x4;
typedef __attribute__((ext_vector_type(8))) __bf16 bf16x8;
typedef __attribute__((ext_vector_type(8))) short short8;
typedef __attribute__((ext_vector_type(4))) unsigned short ushort4v;
typedef unsigned short u16;

static __device__ __forceinline__ f32x4 mfma16(short8 a, short8 b, f32x4 c) {
  return __builtin_amdgcn_mfma_f32_16x16x32_bf16(
      __builtin_bit_cast(bf16x8, a), __builtin_bit_cast(bf16x8, b), c, 0, 0, 0);
}
static __device__ __forceinline__ u16 f2bf(float f) {
  unsigned u = __float_as_uint(f);
  u += 0x7FFFu + ((u >> 16) & 1u);
  return (u16)(u >> 16);
}
static __device__ __forceinline__ float bf2f(u16 h) {
  return __uint_as_float(((unsigned)h) << 16);
}
static __device__ __forceinline__ void lds_load16(const void* g, void* l) {
  __builtin_amdgcn_global_load_lds(
      (const __attribute__((address_space(1))) void*)g,
      (__attribute__((address_space(3))) void*)l, 16, 0, 0);
}

// ---- fused prep: Xq/Xk/Xv bf16 tokens + all weights/bias -> bf16 ----
#define PREP_BLKS (MC / 4 / 256)
#define CONV_N4   ((4 * WSZ + CDIM) / 4)
#define CONV_BLKS ((CONV_N4 + 255) / 256)
__global__ __launch_bounds__(256) void prep_all(
    const float* __restrict__ xp, const float* __restrict__ qp,
    const float* __restrict__ kp, const float* __restrict__ Wq,
    const float* __restrict__ Wk, const float* __restrict__ Wv,
    const float* __restrict__ Wp, const float* __restrict__ bp,
    u16* __restrict__ Xq, u16* __restrict__ Xk, u16* __restrict__ Xv,
    u16* __restrict__ Wb) {
  int bid = blockIdx.x;
  if (bid < PREP_BLKS) {
    int i4 = bid * 256 + threadIdx.x;
    int a4 = i4 % (LC / 4);
    f32x4 xx = ((const f32x4*)xp)[i4];
    f32x4 qq = ((const f32x4*)qp)[a4];
    f32x4 kk = ((const f32x4*)kp)[a4];
    ushort4v oq, ok, ov;
#pragma unroll
    for (int j = 0; j < 4; j++) {
      oq[j] = f2bf(xx[j] + qq[j]);
      ok[j] = f2bf(xx[j] + kk[j]);
      ov[j] = f2bf(xx[j]);
    }
    ((ushort4v*)Xq)[i4] = oq;
    ((ushort4v*)Xk)[i4] = ok;
    ((ushort4v*)Xv)[i4] = ov;
  } else {
    int i4 = (bid - PREP_BLKS) * 256 + threadIdx.x;
    if (i4 >= CONV_N4) return;
    int sel = i4 / (WSZ / 4);
    int off = i4 - sel * (WSZ / 4);
    const float* src = sel == 0 ? Wq : sel == 1 ? Wk : sel == 2 ? Wv
                     : sel == 3 ? Wp : bp;
    f32x4 v = ((const f32x4*)src)[off];
    ushort4v o;
#pragma unroll
    for (int j = 0; j < 4; j++) o[j] = f2bf(v[j]);
    ((ushort4v*)Wb)[i4] = o;
  }
}

// ---- 64x128 (K=768) bf16 GEMM core, DOUBLE-BUFFERED 2-phase (round-13):
// stage next tile's 6 global_load_lds into buf^1, s_waitcnt vmcnt(6),
// raw s_barrier, compute, lgkmcnt(0)+barrier. LDS 48KB.
static __device__ __forceinline__ void gemm_core64_db(
    const u16* __restrict__ Ab, const u16* __restrict__ Wb,
    short* S, f32x4 acc[2][4]) {
  const int t = threadIdx.x;
  const int lane = t & 63, w = t >> 6, quad = lane >> 4, l16 = lane & 15;
  const int wm = (w >> 1) * 32, wn = (w & 1) * 64;
  const int row4 = t >> 2, chunk = (t & 3) * 8;

#define QK_STAGE(K0, BUF) do {                                               \
    short* As_ = S + (BUF) * 12288;                                          \
    short* Bs_ = As_ + 4096;                                                 \
    _Pragma("unroll")                                                        \
    for (int hh = 0; hh < 2; hh++) {                                         \
      const u16* ga = Ab + row4 * CDIM + (K0) + hh * 32 + chunk;             \
      const u16* gb = Wb + row4 * CDIM + (K0) + hh * 32 + chunk;             \
      lds_load16(ga,             (char*)As_ + hh * 4096 + t * 16);           \
      lds_load16(gb,             (char*)Bs_ + hh * 8192 + t * 16);           \
      lds_load16(gb + 64 * CDIM, (char*)Bs_ + hh * 8192 + 4096 + t * 16);    \
    }                                                                        \
  } while (0)

  QK_STAGE(0, 0);
#pragma unroll 1
  for (int ks = 0; ks < 12; ++ks) {
    const int cur = ks & 1;
    if (ks < 11) {
      QK_STAGE((ks + 1) * 64, cur ^ 1);
      asm volatile("s_waitcnt vmcnt(6)" ::: "memory");
    } else {
      asm volatile("s_waitcnt vmcnt(0)" ::: "memory");
    }
    __builtin_amdgcn_s_barrier();
    __builtin_amdgcn_sched_barrier(0);
    const short* Asb = S + cur * 12288;
    const short* Bsb = Asb + 4096;
#pragma unroll
    for (int hh = 0; hh < 2; hh++) {
      const short* Ah = Asb + hh * 2048;
      const short* Bh = Bsb + hh * 4096;
      short8 af[2], bw[4];
#pragma unroll
      for (int i = 0; i < 2; i++)
        af[i] = *(const short8*)(Ah + (wm + i * 16 + l16) * 32 + quad * 8);
#pragma unroll
      for (int j = 0; j < 4; j++)
        bw[j] = *(const short8*)(Bh + (wn + j * 16 + l16) * 32 + quad * 8);
#pragma unroll
      for (int i = 0; i < 2; i++)
#pragma unroll
        for (int j = 0; j < 4; j++)
          acc[i][j] = mfma16(af[i], bw[j], acc[i][j]);
    }
    asm volatile("s_waitcnt lgkmcnt(0)" ::: "memory");
    __builtin_amdgcn_s_barrier();
    __builtin_amdgcn_sched_barrier(0);
  }
#undef QK_STAGE
}

// ---- QKV projections (64x128, 2-phase) + pos repack tail + XCD-clustered
// decode. 1D grid 1536: ids >= 1152 -> repack (runs as tail, unchanged).
// GEMM ids: k8 = id&7 is the XCD under round-robin dispatch; each XCD owns
// y in [k8*8, k8*8+8) for all (z,x) -> the 6 n-blocks sharing an A-panel
// and the 3 z's A-panels stay in ONE XCD's L2 (2.4MB A + 3.5MB W working
// set), instead of re-fetching A from HBM on 6 XCDs. Bijective decode:
// y = k8*8 + (m&7); rem2 = m>>3 in [0,18): z = rem2/6, x = rem2%6.
__global__ __launch_bounds__(256) void gemm_qkv(
    const u16* __restrict__ Xq, const u16* __restrict__ Xk, const u16* __restrict__ Xv,
    const u16* __restrict__ Wq, const u16* __restrict__ Wk, const u16* __restrict__ Wv,
    u16* __restrict__ Q, u16* __restrict__ K, u16* __restrict__ Vt,
    const float* __restrict__ pos, u16* __restrict__ posT) {
  __shared__ __align__(16) short S[24576];   // 48KB: 2 x (A 4096 + B 8192)
  const int id = blockIdx.x;
  if (id >= 1152) {
    const int t = threadIdx.x, wv = t >> 6, lane = t & 63;
    const int flat = id - 1152;                     // 0..383
    const int rr = lane >> 2, cq = lane & 3;
    const int quad = lane >> 4, l16 = lane & 15;
    float* Lw = (float*)S + wv * (16 * LTS);
#pragma unroll 1
    for (int c = 0; c < 8; ++c) {
      const int chunk = flat * 32 + wv * 8 + c;     // 0..12287
      const int h = chunk >> 10, rem = chunk & 1023;
      const int rb = rem >> 4, kt = rem & 15;
      const float* src = pos + (size_t)h * SEQ * SEQ
                         + (size_t)(rb * 16) * SEQ + kt * 64;
#pragma unroll
      for (int u = 0; u < 4; u++) {
        f32x4 v = *(const f32x4*)(src + rr * SEQ + cq * 16 + u * 4);
        *(f32x4*)(Lw + rr * LTS + cq * 16 + u * 4) = v;
      }
      __builtin_amdgcn_s_waitcnt(0xC07F);   // lgkmcnt(0), per-wave
      short8 s0, s1;
#pragma unroll
      for (int j = 0; j < 2; j++)
#pragma unroll
        for (int r = 0; r < 4; r++) {
          s0[j * 4 + r] = (short)f2bf(Lw[(quad * 4 + r) * LTS + j * 16 + l16] * L2E);
          s1[j * 4 + r] = (short)f2bf(Lw[(quad * 4 + r) * LTS + (j + 2) * 16 + l16] * L2E);
        }
      u16* dst = posT + (size_t)chunk * 1024 + lane * 16;
      *(short8*)dst = s0;
      *(short8*)(dst + 8) = s1;
      __builtin_amdgcn_s_waitcnt(0xC07F);   // drain LDS reads before overwrite
    }
    return;
  }

  // XCD-clustered GEMM decode
  const int k8 = id & 7, m = id >> 3;        // m in [0,144)
  const int y = k8 * 8 + (m & 7);            // y in [0,64)
  const int rem2 = m >> 3;                   // [0,18)
  const int z = rem2 / 6, x = rem2 - z * 6;
  const int m0 = y * 64, n0 = x * 128;
  const u16* A = (z == 0 ? Xq : z == 1 ? Xk : Xv) + m0 * CDIM;
  const u16* W = (z == 0 ? Wq : z == 1 ? Wk : Wv) + n0 * CDIM;
  f32x4 acc[2][4];
#pragma unroll
  for (int i = 0; i < 2; i++)
#pragma unroll
    for (int j = 0; j < 4; j++) acc[i][j] = 0.f;
  gemm_core64_db(A, W, S, acc);

  const int t = threadIdx.x, lane = t & 63, w = t >> 6;
  const int quad = lane >> 4, l16 = lane & 15;
  const int wm = (w >> 1) * 32, wn = (w & 1) * 64;
  const float qs = (z == 0) ? 0.125f : 1.0f;

  __syncthreads();   // all compute done before S is reused by the epilogue
#pragma unroll
  for (int i = 0; i < 2; i++)
#pragma unroll
    for (int j = 0; j < 4; j++)
#pragma unroll
      for (int r = 0; r < 4; r++) {
        int mr = wm + i * 16 + quad * 4 + r;
        int nc = wn + j * 16 + l16;
        if (z < 2) S[mr * EST + nc] = (short)f2bf(acc[i][j][r] * qs);
        else       S[nc * VST + mr] = (short)f2bf(acc[i][j][r]);
      }
  __syncthreads();

  const int row = t >> 3, ch = t & 7;
  const int b = m0 >> 10, lbase = m0 & 1023;
  if (z == 0) {
#pragma unroll
    for (int cp = 0; cp < 2; cp++) {
      int h = (n0 >> 6) + cp;
#pragma unroll
      for (int rp = 0; rp < 2; rp++) {
        int mr = row + rp * 32;
        short8 v = *(const short8*)(S + mr * EST + cp * 64 + ch * 8);
        *(short8*)(Q + ((((size_t)(b * NH + h)) << 10) + lbase + mr) * HD + ch * 8) = v;
      }
    }
  } else if (z == 1) {
#pragma unroll
    for (int cp = 0; cp < 2; cp++) {
      int h = (n0 >> 6) + cp;
      u16* Kp = K + (size_t)(b * NH + h) * BHSZ;
#pragma unroll
      for (int rp = 0; rp < 2; rp++) {
        int mr = row + rp * 32;
        int tok = lbase + mr;
        short8 v = *(const short8*)(S + mr * EST + cp * 64 + ch * 8);
        *(short8*)(Kp + (((tok >> 4) * 8 + ch) * 16 + (tok & 15)) * 8) = v;
      }
    }
  } else {
#pragma unroll
    for (int rp = 0; rp < 4; rp++) {
      int rn = row + rp * 32;            // local d-row of transposed tile (n-dim)
      int h = (n0 + rn) >> 6, d = rn & 63;
      u16* Vp = Vt + (size_t)(b * NH + h) * BHSZ;
      int jv = d >> 4, ld16 = d & 15;
      int tok = lbase + ch * 8;          // m-dim: 64 tokens in this block
      short8 v = *(const short8*)(S + rn * VST + ch * 8);
      *(short8*)(Vp + ((((tok >> 6) * 4 + jv) * 8 + ((tok >> 3) & 7)) * 16 + ld16) * 8) = v;
    }
  }
}

// ---- flash attention: round-0 schedule, pos from posT (2 short8/tile) ----
__global__ __launch_bounds__(256, 3) void attn(
    const u16* __restrict__ Q, const u16* __restrict__ Kf, const u16* __restrict__ Vf,
    const u16* __restrict__ posT, u16* __restrict__ O) {
  __shared__ __align__(16) short Ps[4 * 16 * LST];
  const int t = threadIdx.x, lane = t & 63, w = t >> 6;
  const int quad = lane >> 4, l16 = lane & 15;

  // XCD-clustered decode (round-robin lid%8 -> XCD; permutation only)
  const int lid = blockIdx.x;
  const int k8 = lid & 7, m = lid >> 3;
  const int g = k8 * 24 + (m >> 2), b = m & 3;
  const int h = g >> 4, qt = g & 15;
  const int bh = b * NH + h;
  const int q0 = qt * 64 + w * 16;

  const u16* Kg = Kf + (size_t)bh * BHSZ;
  const u16* Vg = Vf + (size_t)bh * BHSZ;
  const u16* Tg = posT + ((size_t)(h * 1024 + (qt * 4 + w) * 16)) * 1024
                  + lane * 16;
  short* Pw = Ps + w * 16 * LST;
  const int fo = quad * 128 + l16 * 8;   // fragment offset (shorts)

  const u16* Qg = Q + ((size_t)bh * SEQ + q0) * HD;
  const short8 qa0 = *(const short8*)(Qg + l16 * HD + quad * 8);
  const short8 qa1 = *(const short8*)(Qg + l16 * HD + 32 + quad * 8);

  f32x4 o[4];
  float lrow[4];
#pragma unroll
  for (int j = 0; j < 4; j++) o[j] = 0.f;
#pragma unroll
  for (int r = 0; r < 4; r++) lrow[r] = 0.f;

  short8 kb0[4], kb1[4];
  short8 pt0, pt1;
#pragma unroll
  for (int j = 0; j < 4; j++) {
    kb0[j] = *(const short8*)(Kg + j * 1024 + fo);
    kb1[j] = *(const short8*)(Kg + j * 1024 + 512 + fo);
  }
  pt0 = *(const short8*)(Tg);
  pt1 = *(const short8*)(Tg + 8);

#pragma unroll 1
  for (int kt = 0; kt < 16; ++kt) {
    const int kbase = kt * 4096;
    short8 vb0[4], vb1[4];
#pragma unroll
    for (int j = 0; j < 4; j++) {
      vb0[j] = *(const short8*)(Vg + kbase + j * 1024 + fo);
      vb1[j] = *(const short8*)(Vg + kbase + j * 1024 + 512 + fo);
    }
    f32x4 s[4];
#pragma unroll
    for (int j = 0; j < 4; j++) {
      f32x4 zz = 0.f;
      s[j] = mfma16(qa1, kb1[j], mfma16(qa0, kb0[j], zz));
    }
#pragma unroll
    for (int j = 0; j < 2; j++)
#pragma unroll
      for (int r = 0; r < 4; r++) {
        float pv = bf2f((u16)pt0[j * 4 + r]);
        float e = __builtin_amdgcn_exp2f(fmaf(s[j][r], L2E, pv));
        unsigned bits = __float_as_uint(e);
        Pw[(quad * 4 + r) * LST + j * 16 + l16] = (short)(bits >> 16);
        lrow[r] += __uint_as_float(bits & 0xFFFF0000u);
      }
#pragma unroll
    for (int j = 2; j < 4; j++)
#pragma unroll
      for (int r = 0; r < 4; r++) {
        float pv = bf2f((u16)pt1[(j - 2) * 4 + r]);
        float e = __builtin_amdgcn_exp2f(fmaf(s[j][r], L2E, pv));
        unsigned bits = __float_as_uint(e);
        Pw[(quad * 4 + r) * LST + j * 16 + l16] = (short)(bits >> 16);
        lrow[r] += __uint_as_float(bits & 0xFFFF0000u);
      }
    if (kt < 15) {
      const int nb = kbase + 4096;
#pragma unroll
      for (int j = 0; j < 4; j++) {
        kb0[j] = *(const short8*)(Kg + nb + j * 1024 + fo);
        kb1[j] = *(const short8*)(Kg + nb + j * 1024 + 512 + fo);
      }
      pt0 = *(const short8*)(Tg + (kt + 1) * 1024);
      pt1 = *(const short8*)(Tg + (kt + 1) * 1024 + 8);
    }
    const short8 pa0 = *(const short8*)(Pw + l16 * LST + quad * 8);
    const short8 pa1 = *(const short8*)(Pw + l16 * LST + 32 + quad * 8);
#pragma unroll
    for (int j = 0; j < 4; j++)
      o[j] = mfma16(pa1, vb1[j], mfma16(pa0, vb0[j], o[j]));
  }

#pragma unroll
  for (int off = 1; off < 16; off <<= 1)
#pragma unroll
    for (int r = 0; r < 4; r++) lrow[r] += __shfl_xor(lrow[r], off);

  u16* Og = O + ((size_t)b * SEQ + q0) * CDIM + h * HD;
  float inv[4];
#pragma unroll
  for (int r = 0; r < 4; r++) inv[r] = 1.0f / lrow[r];
#pragma unroll
  for (int j = 0; j < 4; j++)
#pragma unroll
    for (int r = 0; r < 4; r++)
      Og[(quad * 4 + r) * CDIM + j * 16 + l16] = f2bf(o[j][r] * inv[r]);
}

// ---- output projection + bias, FP32 output. 64x64 tiles, 768 blocks = 3/CU.
__global__ __launch_bounds__(256) void gemm_proj(
    const u16* __restrict__ Oin, const u16* __restrict__ Wp,
    const u16* __restrict__ bp, float* __restrict__ out) {
  __shared__ __align__(16) short As[4096], Bs[4096];   // 16KB
  const int t = threadIdx.x;
  const int lane = t & 63, w = t >> 6, quad = lane >> 4, l16 = lane & 15;
  const int wm = (w >> 1) * 32, wn = (w & 1) * 32;
  const int row4 = t >> 2, chunk = (t & 3) * 8;
  const int m0 = blockIdx.y * 64, n0 = blockIdx.x * 64;
  const u16* Ab = Oin + m0 * CDIM;
  const u16* Wb = Wp + n0 * CDIM;
  f32x4 acc[2][2];
#pragma unroll
  for (int i = 0; i < 2; i++)
#pragma unroll
    for (int j = 0; j < 2; j++) acc[i][j] = 0.f;

  for (int k0 = 0; k0 < CDIM; k0 += 64) {
#pragma unroll
    for (int hh = 0; hh < 2; hh++) {
      const u16* ga = Ab + row4 * CDIM + k0 + hh * 32 + chunk;
      const u16* gb = Wb + row4 * CDIM + k0 + hh * 32 + chunk;
      lds_load16(ga, (char*)As + hh * 4096 + t * 16);
      lds_load16(gb, (char*)Bs + hh * 4096 + t * 16);
    }
    __syncthreads();
#pragma unroll
    for (int hh = 0; hh < 2; hh++) {
      const short* Ah = As + hh * 2048;
      const short* Bh = Bs + hh * 2048;
      short8 af[2], bw[2];
#pragma unroll
      for (int i = 0; i < 2; i++)
        af[i] = *(const short8*)(Ah + (wm + i * 16 + l16) * 32 + quad * 8);
#pragma unroll
      for (int j = 0; j < 2; j++)
        bw[j] = *(const short8*)(Bh + (wn + j * 16 + l16) * 32 + quad * 8);
#pragma unroll
      for (int i = 0; i < 2; i++)
#pragma unroll
        for (int j = 0; j < 2; j++)
          acc[i][j] = mfma16(af[i], bw[j], acc[i][j]);
    }
    __syncthreads();
  }

#pragma unroll
  for (int i = 0; i < 2; i++) {
    int mrow = m0 + wm + i * 16 + quad * 4;
#pragma unroll
    for (int j = 0; j < 2; j++) {
      int n = n0 + wn + j * 16 + l16;
      float bias = bf2f(bp[n]);
#pragma unroll
      for (int r = 0; r < 4; r++)
        out[(mrow + r) * CDIM + n] = acc[i][j][r] + bias;
    }
  }
}

extern "C" void kernel_launch(void* const* d_in, const int* in_sizes, int n_in,
                              void* d_out, int out_size, void* d_ws, size_t ws_size,
                              hipStream_t stream) {
  (void)in_sizes; (void)n_in; (void)out_size;
  const size_t OFF_XQ = 0, OFF_XK = (size_t)MC, OFF_XV = 2ull * MC,
               OFF_Q = 3ull * MC, OFF_K = 4ull * MC, OFF_VT = 5ull * MC,
               OFF_W = 6ull * MC, OFF_PT = OFF_W + 4ull * WSZ + 1024,
               TOT = OFF_PT + PTSZ;
  if (ws_size < TOT * sizeof(u16)) return;

  u16* ws = (u16*)d_ws;
  u16 *Xq = ws + OFF_XQ, *Xk = ws + OFF_XK, *Xv = ws + OFF_XV;
  u16 *Qb = ws + OFF_Q, *Kb = ws + OFF_K, *Vt = ws + OFF_VT;
  u16 *Wb = ws + OFF_W, *Pt = ws + OFF_PT;
  u16 *Wqb = Wb, *Wkb = Wb + WSZ, *Wvb = Wb + 2ull * WSZ,
      *Wpb = Wb + 3ull * WSZ, *bpb = Wb + 4ull * WSZ;
  u16* Ob = Xq;

  prep_all<<<PREP_BLKS + CONV_BLKS, 256, 0, stream>>>(
      (const float*)d_in[0], (const float*)d_in[1], (const float*)d_in[2],
      (const float*)d_in[4], (const float*)d_in[5], (const float*)d_in[6],
      (const float*)d_in[7], (const float*)d_in[8], Xq, Xk, Xv, Wb);
  gemm_qkv<<<dim3(1536), 256, 0, stream>>>(Xq, Xk, Xv, Wqb, Wkb, Wvb,
                                           Qb, Kb, Vt,
                                           (const float*)d_in[3], Pt);
  attn<<<dim3(768), 256, 0, stream>>>(Qb, Kb, Vt, Pt, Ob);
  gemm_proj<<<dim3(12, 64), 256, 0, stream>>>(Ob, Wpb, bpb, (float*)d_out);
}